// Round 5
// baseline (331.557 us; speedup 1.0000x reference)
//
#include <hip/hip_runtime.h>
#include <cstdint>

typedef unsigned short u16;
typedef unsigned int   u32;
typedef _Float16 f16;

typedef __attribute__((ext_vector_type(8))) _Float16 f16x8;   // 8 fp16 = 4 VGPRs
typedef __attribute__((ext_vector_type(4))) float    f32x4;   // MFMA accumulator

__device__ __forceinline__ u16 f2h(float f) {
    union { f16 h; u16 u; } c; c.h = (f16)f; return c.u;      // v_cvt_f16_f32 RTNE
}

// async global->LDS, 16B per lane; LDS dest = wave-uniform base + lane*16
__device__ __forceinline__ void async_copy16(const u16* g, u16* lds) {
    __builtin_amdgcn_global_load_lds(
        (const __attribute__((address_space(1))) void*)g,
        (__attribute__((address_space(3))) void*)lds,
        16, 0, 0);
}

// ---------------------------------------------------------------------------
// fp16 NT GEMM core (pre-converted f16 operands): C[128,128] += A*B^T.
// 256 thr = 4 waves (2x2), each wave 64x64 = 4x4 MFMA 16x16x32.  BK=32.
// LDS: As[128][32] + Bs[128][32] u16 = 16 KB, XOR-swizzled k-chunks:
// logical chunk kc of row r lives at physical chunk kc ^ ((r>>1)&3).
// ---------------------------------------------------------------------------
__device__ __forceinline__ void gemm_nt_f16(
    u16* smem, const u16* __restrict__ A, int lda,
    const u16* __restrict__ B, int ldb, int K, f32x4 acc[4][4])
{
    u16* As = smem; u16* Bs = smem + 4096;
    const int t = threadIdx.x, w = t >> 6, lane = t & 63;
    const int srow = lane >> 2;
    const int skc  = (((lane & 3) ^ ((lane >> 3) & 3)) * 8);
    const int ra0 = (w*2+0)*16 + srow, ra1 = (w*2+1)*16 + srow;
    const u16* gA0 = A + (size_t)ra0 * lda + skc;
    const u16* gA1 = A + (size_t)ra1 * lda + skc;
    const u16* gB0 = B + (size_t)ra0 * ldb + skc;
    const u16* gB1 = B + (size_t)ra1 * ldb + skc;
    u16* lA0 = As + (w*2+0)*512; u16* lA1 = As + (w*2+1)*512;
    u16* lB0 = Bs + (w*2+0)*512; u16* lB1 = Bs + (w*2+1)*512;
    const int fr = lane & 15, fq = lane >> 4;
    const int fc = (fq ^ ((fr >> 1) & 3)) * 8;
    const int wm = (w >> 1) * 64, wn = (w & 1) * 64;
    const u16* fA = As + (wm + fr) * 32 + fc;
    const u16* fB = Bs + (wn + fr) * 32 + fc;

    for (int k0 = 0; k0 < K; k0 += 32) {
        async_copy16(gA0 + k0, lA0);
        async_copy16(gA1 + k0, lA1);
        async_copy16(gB0 + k0, lB0);
        async_copy16(gB1 + k0, lB1);
        __syncthreads();
        f16x8 af[4], bf[4];
#pragma unroll
        for (int i = 0; i < 4; i++) af[i] = *(const f16x8*)(fA + i * 512);
#pragma unroll
        for (int i = 0; i < 4; i++) bf[i] = *(const f16x8*)(fB + i * 512);
#pragma unroll
        for (int mi = 0; mi < 4; mi++)
#pragma unroll
            for (int ni = 0; ni < 4; ni++)
                acc[mi][ni] = __builtin_amdgcn_mfma_f32_16x16x32_f16(
                    af[mi], bf[ni], acc[mi][ni], 0, 0, 0);
        __syncthreads();
    }
}

__device__ __forceinline__ void zero_acc(f32x4 acc[4][4]) {
#pragma unroll
    for (int i = 0; i < 4; i++)
#pragma unroll
        for (int j = 0; j < 4; j++) {
            f32x4 z = {0.f, 0.f, 0.f, 0.f};
            acc[i][j] = z;
        }
}

// ---------------------------------------------------------------------------
// Kernel W: convert wq/wk/wv f32 -> f16, packed [3][512][512]
// ---------------------------------------------------------------------------
__global__ __launch_bounds__(256) void k_convw(const float* __restrict__ wq,
                                               const float* __restrict__ wk,
                                               const float* __restrict__ wv,
                                               u16* __restrict__ Wf)
{
    const int t = blockIdx.x * 256 + threadIdx.x;
    const int e = t * 4;
    const int sel = e >> 18;
    const int off = e & 262143;
    const float* src = (sel == 0) ? wq : (sel == 1) ? wk : wv;
    float4 v = *(const float4*)(src + off);
    ushort4 h;
    h.x = f2h(v.x); h.y = f2h(v.y); h.z = f2h(v.z); h.w = f2h(v.w);
    *(ushort4*)(Wf + sel * 262144 + off) = h;
}

// ---------------------------------------------------------------------------
// Kernel 1 (FUSED transpose): Q/K/V = W*X + bias, reading X f32 directly.
// A = Wf (f16, global_load_lds).  B-tile staged from X[c,n] f32 with an
// in-register f32->f16 convert + transposed swizzled ds_write_b32.
// Lane map: nn=t&15, cg=t>>4 (c-pair 2cg,2cg+1), nb=0..7 -> n=nn+16*nb.
// Write banks: 32 distinct, 2 lanes each (nn vs nn+8) = 2-way = free.
// B loads for iter k+1 prefetched after barrier to hide under MFMA.
// grid (32 ntiles, 12 mtiles, 8 b); mtile 0-3 Q, 4-7 K, 8-11 V.
// ---------------------------------------------------------------------------
__global__ __launch_bounds__(256) void k_qkv(
    const u16* __restrict__ Wf,
    const float* __restrict__ bq, const float* __restrict__ bk, const float* __restrict__ bv,
    const float* __restrict__ x,
    u16* __restrict__ Qh, u16* __restrict__ Kh, u16* __restrict__ VT)
{
    __shared__ u16 smem[8192];           // As[128][32] + Bs[128][32] = 16 KB
    u16* As = smem; u16* Bs = smem + 4096;
    const int n0  = blockIdx.x * 128;
    const int my  = blockIdx.y;
    const int b   = blockIdx.z;
    const int sel = my >> 2;
    const int m0  = (my & 3) * 128;

    const float* bi = (sel == 0) ? bq : (sel == 1) ? bk : bv;
    const u16* A = Wf + (size_t)sel * 262144 + (size_t)m0 * 512;

    const int t = threadIdx.x, w = t >> 6, lane = t & 63;

    // ---- A staging (global_load_lds, swizzled) ----
    const int srow = lane >> 2;
    const int skc  = (((lane & 3) ^ ((lane >> 3) & 3)) * 8);
    const int ra0 = (w*2+0)*16 + srow, ra1 = (w*2+1)*16 + srow;
    const u16* gA0 = A + (size_t)ra0 * 512 + skc;
    const u16* gA1 = A + (size_t)ra1 * 512 + skc;
    u16* lA0 = As + (w*2+0)*512; u16* lA1 = As + (w*2+1)*512;

    // ---- B staging from x (f32 -> f16 transposed) ----
    const int nn = t & 15;               // n within 16-group
    const int cg = t >> 4;               // 0..15 -> c-pair (2cg, 2cg+1)
    const float* xb = x + ((size_t)b * 512 + 2 * cg) * 4096 + n0 + nn;
    const int chunkB = (cg >> 2) ^ ((nn >> 1) & 3);
    u16* lB = Bs + nn * 32 + chunkB * 8 + ((2 * cg) & 7);   // + nb*512

    // ---- fragment read addresses ----
    const int fr = lane & 15, fq = lane >> 4;
    const int fc = (fq ^ ((fr >> 1) & 3)) * 8;
    const int wm = (w >> 1) * 64, wn = (w & 1) * 64;
    const u16* fA = As + (wm + fr) * 32 + fc;
    const u16* fB = Bs + (wn + fr) * 32 + fc;

    f32x4 acc[4][4];
    zero_acc(acc);

    // prefetch B regs for k0 = 0
    float va[8], vb[8];
#pragma unroll
    for (int nb = 0; nb < 8; nb++) {
        va[nb] = xb[nb * 16];
        vb[nb] = xb[4096 + nb * 16];
    }

    for (int k0 = 0; k0 < 512; k0 += 32) {
        async_copy16(gA0 + k0, lA0);
        async_copy16(gA1 + k0, lA1);
        // commit current B regs to LDS (transposed, packed c-pair)
#pragma unroll
        for (int nb = 0; nb < 8; nb++) {
            u32 pk = (u32)f2h(va[nb]) | ((u32)f2h(vb[nb]) << 16);
            *(u32*)(lB + nb * 512) = pk;
        }
        __syncthreads();                 // drains A-async + B ds_writes

        // prefetch B regs for next iteration (hidden under MFMA)
        const int kn = (k0 + 32 < 512) ? (k0 + 32) : 0;
        const float* xk = xb + (size_t)kn * 4096;
#pragma unroll
        for (int nb = 0; nb < 8; nb++) {
            va[nb] = xk[nb * 16];
            vb[nb] = xk[4096 + nb * 16];
        }

        f16x8 af[4], bf[4];
#pragma unroll
        for (int i = 0; i < 4; i++) af[i] = *(const f16x8*)(fA + i * 512);
#pragma unroll
        for (int i = 0; i < 4; i++) bf[i] = *(const f16x8*)(fB + i * 512);
#pragma unroll
        for (int mi = 0; mi < 4; mi++)
#pragma unroll
            for (int ni = 0; ni < 4; ni++)
                acc[mi][ni] = __builtin_amdgcn_mfma_f32_16x16x32_f16(
                    af[mi], bf[ni], acc[mi][ni], 0, 0, 0);
        __syncthreads();
    }

    const int cn = lane & 15, cq = lane >> 4;

    if (sel < 2) {
        u16* out = ((sel == 0) ? Qh : Kh) + (size_t)b * 512 * 4096;
#pragma unroll
        for (int mi = 0; mi < 4; mi++)
#pragma unroll
            for (int ni = 0; ni < 4; ni++)
#pragma unroll
                for (int r = 0; r < 4; r++) {
                    int m = wm + mi * 16 + cq * 4 + r;
                    int n = wn + ni * 16 + cn;
                    out[(size_t)(m0 + m) * 4096 + n0 + n] =
                        f2h(acc[mi][ni][r] + bi[m0 + m]);
                }
    } else {
        u16* out = VT + (size_t)b * 4096 * 512;
#pragma unroll
        for (int mi = 0; mi < 4; mi++)
#pragma unroll
            for (int ni = 0; ni < 4; ni++) {
                int n  = wn + ni * 16 + cn;
                int mb = wm + mi * 16 + cq * 4;
                ushort4 pk;
                pk.x = f2h(acc[mi][ni][0] + bi[m0 + mb + 0]);
                pk.y = f2h(acc[mi][ni][1] + bi[m0 + mb + 1]);
                pk.z = f2h(acc[mi][ni][2] + bi[m0 + mb + 2]);
                pk.w = f2h(acc[mi][ni][3] + bi[m0 + mb + 3]);
                *(ushort4*)(out + (size_t)(n0 + n) * 512 + m0 + mb) = pk;
            }
    }
}

// ---------------------------------------------------------------------------
// Kernel 2: S = Q*K^T (fp16 in, fp32 out), split-K=4.  grid (4,4,32)
// S layout: [ks][b][512][512] fp32
// ---------------------------------------------------------------------------
__global__ __launch_bounds__(256) void k_scores(const u16* __restrict__ Qh,
                                                const u16* __restrict__ Kh,
                                                float* __restrict__ S)
{
    __shared__ u16 smem[8192];
    const int n0 = blockIdx.x * 128;
    const int m0 = blockIdx.y * 128;
    const int bz = blockIdx.z;
    const int b  = bz >> 2, ks = bz & 3;

    const u16* Ap = Qh + (size_t)b * 512 * 4096 + (size_t)m0 * 4096 + ks * 1024;
    const u16* Bp = Kh + (size_t)b * 512 * 4096 + (size_t)n0 * 4096 + ks * 1024;

    f32x4 acc[4][4];
    zero_acc(acc);
    gemm_nt_f16(smem, Ap, 4096, Bp, 4096, 1024, acc);

    const int t = threadIdx.x, w = t >> 6, lane = t & 63;
    const int wm = (w >> 1) * 64, wn = (w & 1) * 64;
    const int cn = lane & 15, cq = lane >> 4;

    float* out = S + ((size_t)(ks * 8 + b) * 512 + m0) * 512 + n0;
#pragma unroll
    for (int mi = 0; mi < 4; mi++)
#pragma unroll
        for (int ni = 0; ni < 4; ni++)
#pragma unroll
            for (int r = 0; r < 4; r++) {
                int m = wm + mi * 16 + cq * 4 + r;
                int n = wn + ni * 16 + cn;
                out[(size_t)m * 512 + n] = acc[mi][ni][r];
            }
}

// ---------------------------------------------------------------------------
// Kernel 3: softmax rows of (S0+S1+S2+S3) -> P f16 [b][512][512]
// ---------------------------------------------------------------------------
__global__ __launch_bounds__(256) void k_softmax(const float* __restrict__ S,
                                                 u16* __restrict__ P)
{
    const int row = blockIdx.x;              // b*512 + c
    const int t = threadIdx.x, w = t >> 6, lane = t & 63;
    const size_t st = (size_t)8 * 512 * 512;
    const float* r0 = S + (size_t)row * 512;

    float v0 = r0[t]       + r0[t + st]       + r0[t + 2*st]       + r0[t + 3*st];
    float v1 = r0[t + 256] + r0[t + 256 + st] + r0[t + 256 + 2*st] + r0[t + 256 + 3*st];

    float m = fmaxf(v0, v1);
    for (int o = 32; o; o >>= 1) m = fmaxf(m, __shfl_xor(m, o));
    __shared__ float redm[4];
    if (lane == 0) redm[w] = m;
    __syncthreads();
    m = fmaxf(fmaxf(redm[0], redm[1]), fmaxf(redm[2], redm[3]));

    float e0 = __expf(v0 - m), e1 = __expf(v1 - m);
    float s = e0 + e1;
    for (int o = 32; o; o >>= 1) s += __shfl_xor(s, o);
    __shared__ float reds[4];
    if (lane == 0) reds[w] = s;
    __syncthreads();
    s = reds[0] + reds[1] + reds[2] + reds[3];

    float inv = 1.0f / s;
    P[(size_t)row * 512 + t]       = f2h(e0 * inv);
    P[(size_t)row * 512 + t + 256] = f2h(e1 * inv);
}

// ---------------------------------------------------------------------------
// Kernel 4: out = P*V + X (f32 out).  grid (32, 4, 8)
// ---------------------------------------------------------------------------
__global__ __launch_bounds__(256) void k_out(const u16* __restrict__ P,
                                             const u16* __restrict__ VT,
                                             const float* __restrict__ x,
                                             float* __restrict__ out)
{
    __shared__ u16 smem[8192];
    const int n0 = blockIdx.x * 128;
    const int m0 = blockIdx.y * 128;
    const int b  = blockIdx.z;

    const u16* Ap = P  + (size_t)b * 512 * 512 + (size_t)m0 * 512;
    const u16* Bp = VT + (size_t)b * 4096 * 512 + (size_t)n0 * 512;

    f32x4 acc[4][4];
    zero_acc(acc);
    gemm_nt_f16(smem, Ap, 512, Bp, 512, 512, acc);

    const int t = threadIdx.x, w = t >> 6, lane = t & 63;
    const int wm = (w >> 1) * 64, wn = (w & 1) * 64;
    const int cn = lane & 15, cq = lane >> 4;

#pragma unroll
    for (int mi = 0; mi < 4; mi++)
#pragma unroll
        for (int ni = 0; ni < 4; ni++)
#pragma unroll
            for (int r = 0; r < 4; r++) {
                int m = wm + mi * 16 + cq * 4 + r;
                int n = wn + ni * 16 + cn;
                size_t idx = ((size_t)b * 512 + m0 + m) * 4096 + n0 + n;
                out[idx] = acc[mi][ni][r] + x[idx];
            }
}

// ---------------------------------------------------------------------------
// ws layout (bytes), high-water ~133.5 MiB:
//   Wf  [3][512][512] f16    @ 0          (1572864)
//   Qh  [8][512][4096] f16   @ 1572864    (33554432)
//   Kh  [8][512][4096] f16   @ 35127296   (33554432)
//   VT  [8][4096][512] f16   @ 68681728   (33554432)
//   S   [4][8][512][512] f32 @ 102236160  (33554432)
//   P   [8][512][512] f16    @ 135790592  (4194304)
// ---------------------------------------------------------------------------
extern "C" void kernel_launch(void* const* d_in, const int* in_sizes, int n_in,
                              void* d_out, int out_size, void* d_ws, size_t ws_size,
                              hipStream_t stream)
{
    const float* x  = (const float*)d_in[0];
    const float* wq = (const float*)d_in[1];
    const float* bq = (const float*)d_in[2];
    const float* wk = (const float*)d_in[3];
    const float* bk = (const float*)d_in[4];
    const float* wv = (const float*)d_in[5];
    const float* bv = (const float*)d_in[6];
    float* out = (float*)d_out;

    char* ws = (char*)d_ws;
    u16*  Wf = (u16*)(ws);
    u16*  Qh = (u16*)(ws + 1572864);
    u16*  Kh = (u16*)(ws + 35127296);
    u16*  VT = (u16*)(ws + 68681728);
    float* S = (float*)(ws + 102236160);
    u16*  P  = (u16*)(ws + 135790592);

    k_convw<<<dim3(768), dim3(256), 0, stream>>>(wq, wk, wv, Wf);
    k_qkv<<<dim3(32, 12, 8), dim3(256), 0, stream>>>(Wf, bq, bk, bv, x, Qh, Kh, VT);
    k_scores<<<dim3(4, 4, 32), dim3(256), 0, stream>>>(Qh, Kh, S);
    k_softmax<<<dim3(4096), dim3(256), 0, stream>>>(S, P);
    k_out<<<dim3(32, 4, 8), dim3(256), 0, stream>>>(P, VT, x, out);
}

// Round 6
// 315.065 us; speedup vs baseline: 1.0523x; 1.0523x over previous
//
#include <hip/hip_runtime.h>
#include <cstdint>

typedef unsigned short u16;
typedef unsigned int   u32;
typedef _Float16 f16;

typedef __attribute__((ext_vector_type(8))) _Float16 f16x8;   // 8 fp16 = 4 VGPRs
typedef __attribute__((ext_vector_type(4))) float    f32x4;   // MFMA accumulator

__device__ __forceinline__ u16 f2h(float f) {
    union { f16 h; u16 u; } c; c.h = (f16)f; return c.u;      // v_cvt_f16_f32 RTNE
}

// async global->LDS, 16B per lane; LDS dest = wave-uniform base + lane*16
__device__ __forceinline__ void async_copy16(const u16* g, u16* lds) {
    __builtin_amdgcn_global_load_lds(
        (const __attribute__((address_space(1))) void*)g,
        (__attribute__((address_space(3))) void*)lds,
        16, 0, 0);
}

// ---------------------------------------------------------------------------
// fp16 NT GEMM core: C[128,128] += A[128,K] * B[128,K]^T, K contiguous both.
// 256 thr = 4 waves (2x2), each wave 64x64 = 4x4 MFMA 16x16x32.  BK=32.
// LDS: As[128][32] + Bs[128][32] u16 = 16 KB, XOR-swizzled k-chunks:
// logical chunk kc of row r lives at physical chunk kc ^ ((r>>1)&3).
// ---------------------------------------------------------------------------
__device__ __forceinline__ void gemm_nt_f16(
    u16* smem, const u16* __restrict__ A, int lda,
    const u16* __restrict__ B, int ldb, int K, f32x4 acc[4][4])
{
    u16* As = smem; u16* Bs = smem + 4096;
    const int t = threadIdx.x, w = t >> 6, lane = t & 63;
    const int srow = lane >> 2;
    const int skc  = (((lane & 3) ^ ((lane >> 3) & 3)) * 8);
    const int ra0 = (w*2+0)*16 + srow, ra1 = (w*2+1)*16 + srow;
    const u16* gA0 = A + (size_t)ra0 * lda + skc;
    const u16* gA1 = A + (size_t)ra1 * lda + skc;
    const u16* gB0 = B + (size_t)ra0 * ldb + skc;
    const u16* gB1 = B + (size_t)ra1 * ldb + skc;
    u16* lA0 = As + (w*2+0)*512; u16* lA1 = As + (w*2+1)*512;
    u16* lB0 = Bs + (w*2+0)*512; u16* lB1 = Bs + (w*2+1)*512;
    const int fr = lane & 15, fq = lane >> 4;
    const int fc = (fq ^ ((fr >> 1) & 3)) * 8;
    const int wm = (w >> 1) * 64, wn = (w & 1) * 64;
    const u16* fA = As + (wm + fr) * 32 + fc;
    const u16* fB = Bs + (wn + fr) * 32 + fc;

    for (int k0 = 0; k0 < K; k0 += 32) {
        async_copy16(gA0 + k0, lA0);
        async_copy16(gA1 + k0, lA1);
        async_copy16(gB0 + k0, lB0);
        async_copy16(gB1 + k0, lB1);
        __syncthreads();
        f16x8 af[4], bf[4];
#pragma unroll
        for (int i = 0; i < 4; i++) af[i] = *(const f16x8*)(fA + i * 512);
#pragma unroll
        for (int i = 0; i < 4; i++) bf[i] = *(const f16x8*)(fB + i * 512);
#pragma unroll
        for (int mi = 0; mi < 4; mi++)
#pragma unroll
            for (int ni = 0; ni < 4; ni++)
                acc[mi][ni] = __builtin_amdgcn_mfma_f32_16x16x32_f16(
                    af[mi], bf[ni], acc[mi][ni], 0, 0, 0);
        __syncthreads();
    }
}

__device__ __forceinline__ void zero_acc(f32x4 acc[4][4]) {
#pragma unroll
    for (int i = 0; i < 4; i++)
#pragma unroll
        for (int j = 0; j < 4; j++) {
            f32x4 z = {0.f, 0.f, 0.f, 0.f};
            acc[i][j] = z;
        }
}

// ---------------------------------------------------------------------------
// Kernel W: convert wq/wk/wv f32 -> f16, packed [3][512][512]
// ---------------------------------------------------------------------------
__global__ __launch_bounds__(256) void k_convw(const float* __restrict__ wq,
                                               const float* __restrict__ wk,
                                               const float* __restrict__ wv,
                                               u16* __restrict__ Wf)
{
    const int t = blockIdx.x * 256 + threadIdx.x;
    const int e = t * 4;
    const int sel = e >> 18;
    const int off = e & 262143;
    const float* src = (sel == 0) ? wq : (sel == 1) ? wk : wv;
    float4 v = *(const float4*)(src + off);
    ushort4 h;
    h.x = f2h(v.x); h.y = f2h(v.y); h.z = f2h(v.z); h.w = f2h(v.w);
    *(ushort4*)(Wf + sel * 262144 + off) = h;
}

// ---------------------------------------------------------------------------
// Kernel 0: transpose+convert X f32 [B,512,4096] -> XT f16 [B,4096,512]
// ---------------------------------------------------------------------------
__global__ __launch_bounds__(256) void k_transpose(const float* __restrict__ x,
                                                   u16* __restrict__ XT)
{
    __shared__ u16 tile[64][70];
    const int t  = threadIdx.x;
    const int b  = blockIdx.z;
    const int c0 = blockIdx.y * 64;
    const int n0 = blockIdx.x * 64;
    const int rr   = t >> 4;
    const int col4 = (t & 15) * 4;

    const float* src = x + ((size_t)b * 512 + c0) * 4096 + n0;
#pragma unroll
    for (int i = 0; i < 4; i++) {
        int row = i * 16 + rr;
        float4 v = *(const float4*)(src + (size_t)row * 4096 + col4);
        ushort4 h;
        h.x = f2h(v.x); h.y = f2h(v.y); h.z = f2h(v.z); h.w = f2h(v.w);
        *(ushort4*)&tile[row][col4] = h;
    }
    __syncthreads();
    u16* dst = XT + ((size_t)b * 4096 + n0) * 512 + c0;
#pragma unroll
    for (int i = 0; i < 4; i++) {
        int nrow = i * 16 + rr;
        ushort4 o;
        o.x = tile[col4 + 0][nrow];
        o.y = tile[col4 + 1][nrow];
        o.z = tile[col4 + 2][nrow];
        o.w = tile[col4 + 3][nrow];
        *(ushort4*)(dst + (size_t)nrow * 512 + col4) = o;
    }
}

// ---------------------------------------------------------------------------
// Kernel 1: QKV from XT.  grid (32 ntiles, 8 my, 8 b).
// my 0..3: MERGED Q+K block — one shared B(X)-tile, two A-tiles (Wq,Wk),
//          32 MFMA per K-iter (2x the MFMA per barrier-pair of round 4).
// my 4..7: V block (m0=(my-4)*128), transposed epilogue -> VT[N,C].
// ---------------------------------------------------------------------------
__global__ __launch_bounds__(256) void k_qkv(
    const u16* __restrict__ Wf,
    const float* __restrict__ bq, const float* __restrict__ bk, const float* __restrict__ bv,
    const u16* __restrict__ XT,
    u16* __restrict__ Qh, u16* __restrict__ Kh, u16* __restrict__ VT)
{
    __shared__ u16 smem[12288];          // QK path: Aq|Ak|B = 24 KB
    const int n0 = blockIdx.x * 128;
    const int my = blockIdx.y;
    const int b  = blockIdx.z;
    const int t = threadIdx.x, w = t >> 6, lane = t & 63;
    const int srow = lane >> 2;
    const int skc  = (((lane & 3) ^ ((lane >> 3) & 3)) * 8);
    const int ra0 = (w*2+0)*16 + srow, ra1 = (w*2+1)*16 + srow;
    const int fr = lane & 15, fq = lane >> 4;
    const int fc = (fq ^ ((fr >> 1) & 3)) * 8;
    const int wm = (w >> 1) * 64, wn = (w & 1) * 64;
    const int cn = lane & 15, cq = lane >> 4;

    const u16* Bp  = XT + ((size_t)b * 4096 + n0) * 512;
    const u16* gB0 = Bp + (size_t)ra0 * 512 + skc;
    const u16* gB1 = Bp + (size_t)ra1 * 512 + skc;

    if (my < 4) {
        // ---------------- merged Q+K ----------------
        const int m0 = my * 128;
        u16* Asq = smem; u16* Ask = smem + 4096; u16* Bs = smem + 8192;
        const u16* Aq = Wf + (size_t)m0 * 512;              // Wq
        const u16* Ak = Wf + 262144 + (size_t)m0 * 512;     // Wk
        const u16* gq0 = Aq + (size_t)ra0 * 512 + skc;
        const u16* gq1 = Aq + (size_t)ra1 * 512 + skc;
        const u16* gk0 = Ak + (size_t)ra0 * 512 + skc;
        const u16* gk1 = Ak + (size_t)ra1 * 512 + skc;
        u16* lq0 = Asq + (w*2+0)*512; u16* lq1 = Asq + (w*2+1)*512;
        u16* lk0 = Ask + (w*2+0)*512; u16* lk1 = Ask + (w*2+1)*512;
        u16* lB0 = Bs  + (w*2+0)*512; u16* lB1 = Bs  + (w*2+1)*512;
        const u16* fAq = Asq + (wm + fr) * 32 + fc;
        const u16* fAk = Ask + (wm + fr) * 32 + fc;
        const u16* fB  = Bs  + (wn + fr) * 32 + fc;

        f32x4 accq[4][4], acck[4][4];
        zero_acc(accq); zero_acc(acck);

        for (int k0 = 0; k0 < 512; k0 += 32) {
            async_copy16(gq0 + k0, lq0);
            async_copy16(gq1 + k0, lq1);
            async_copy16(gk0 + k0, lk0);
            async_copy16(gk1 + k0, lk1);
            async_copy16(gB0 + k0, lB0);
            async_copy16(gB1 + k0, lB1);
            __syncthreads();
            f16x8 aq[4], ak[4], bf[4];
#pragma unroll
            for (int i = 0; i < 4; i++) {
                aq[i] = *(const f16x8*)(fAq + i * 512);
                ak[i] = *(const f16x8*)(fAk + i * 512);
                bf[i] = *(const f16x8*)(fB  + i * 512);
            }
#pragma unroll
            for (int mi = 0; mi < 4; mi++)
#pragma unroll
                for (int ni = 0; ni < 4; ni++) {
                    accq[mi][ni] = __builtin_amdgcn_mfma_f32_16x16x32_f16(
                        aq[mi], bf[ni], accq[mi][ni], 0, 0, 0);
                    acck[mi][ni] = __builtin_amdgcn_mfma_f32_16x16x32_f16(
                        ak[mi], bf[ni], acck[mi][ni], 0, 0, 0);
                }
            __syncthreads();
        }

        u16* oq = Qh + (size_t)b * 512 * 4096;
        u16* ok = Kh + (size_t)b * 512 * 4096;
#pragma unroll
        for (int mi = 0; mi < 4; mi++)
#pragma unroll
            for (int ni = 0; ni < 4; ni++)
#pragma unroll
                for (int r = 0; r < 4; r++) {
                    int m = wm + mi * 16 + cq * 4 + r;
                    int n = wn + ni * 16 + cn;
                    size_t idx = (size_t)(m0 + m) * 4096 + n0 + n;
                    oq[idx] = f2h(accq[mi][ni][r] + bq[m0 + m]);
                    ok[idx] = f2h(acck[mi][ni][r] + bk[m0 + m]);
                }
    } else {
        // ---------------- V ----------------
        const int m0 = (my - 4) * 128;
        const u16* Ap = Wf + (size_t)2 * 262144 + (size_t)m0 * 512;

        f32x4 acc[4][4];
        zero_acc(acc);
        gemm_nt_f16(smem, Ap, 512, Bp, 512, 512, acc);

        u16* out = VT + (size_t)b * 4096 * 512;
#pragma unroll
        for (int mi = 0; mi < 4; mi++)
#pragma unroll
            for (int ni = 0; ni < 4; ni++) {
                int n  = wn + ni * 16 + cn;
                int mb = wm + mi * 16 + cq * 4;
                ushort4 pk;
                pk.x = f2h(acc[mi][ni][0] + bv[m0 + mb + 0]);
                pk.y = f2h(acc[mi][ni][1] + bv[m0 + mb + 1]);
                pk.z = f2h(acc[mi][ni][2] + bv[m0 + mb + 2]);
                pk.w = f2h(acc[mi][ni][3] + bv[m0 + mb + 3]);
                *(ushort4*)(out + (size_t)(n0 + n) * 512 + m0 + mb) = pk;
            }
    }
}

// ---------------------------------------------------------------------------
// Kernel 2: S = Q*K^T (fp16 in, fp32 out), split-K=4.  grid (4,4,32)
// S layout: [ks][b][512][512] fp32
// ---------------------------------------------------------------------------
__global__ __launch_bounds__(256) void k_scores(const u16* __restrict__ Qh,
                                                const u16* __restrict__ Kh,
                                                float* __restrict__ S)
{
    __shared__ u16 smem[8192];
    const int n0 = blockIdx.x * 128;
    const int m0 = blockIdx.y * 128;
    const int bz = blockIdx.z;
    const int b  = bz >> 2, ks = bz & 3;

    const u16* Ap = Qh + (size_t)b * 512 * 4096 + (size_t)m0 * 4096 + ks * 1024;
    const u16* Bp = Kh + (size_t)b * 512 * 4096 + (size_t)n0 * 4096 + ks * 1024;

    f32x4 acc[4][4];
    zero_acc(acc);
    gemm_nt_f16(smem, Ap, 4096, Bp, 4096, 1024, acc);

    const int t = threadIdx.x, w = t >> 6, lane = t & 63;
    const int wm = (w >> 1) * 64, wn = (w & 1) * 64;
    const int cn = lane & 15, cq = lane >> 4;

    float* out = S + ((size_t)(ks * 8 + b) * 512 + m0) * 512 + n0;
#pragma unroll
    for (int mi = 0; mi < 4; mi++)
#pragma unroll
        for (int ni = 0; ni < 4; ni++)
#pragma unroll
            for (int r = 0; r < 4; r++) {
                int m = wm + mi * 16 + cq * 4 + r;
                int n = wn + ni * 16 + cn;
                out[(size_t)m * 512 + n] = acc[mi][ni][r];
            }
}

// ---------------------------------------------------------------------------
// Kernel 3: softmax rows of (S0+S1+S2+S3) -> P f16 [b][512][512]
// ---------------------------------------------------------------------------
__global__ __launch_bounds__(256) void k_softmax(const float* __restrict__ S,
                                                 u16* __restrict__ P)
{
    const int row = blockIdx.x;
    const int t = threadIdx.x, w = t >> 6, lane = t & 63;
    const size_t st = (size_t)8 * 512 * 512;
    const float* r0 = S + (size_t)row * 512;

    float v0 = r0[t]       + r0[t + st]       + r0[t + 2*st]       + r0[t + 3*st];
    float v1 = r0[t + 256] + r0[t + 256 + st] + r0[t + 256 + 2*st] + r0[t + 256 + 3*st];

    float m = fmaxf(v0, v1);
    for (int o = 32; o; o >>= 1) m = fmaxf(m, __shfl_xor(m, o));
    __shared__ float redm[4];
    if (lane == 0) redm[w] = m;
    __syncthreads();
    m = fmaxf(fmaxf(redm[0], redm[1]), fmaxf(redm[2], redm[3]));

    float e0 = __expf(v0 - m), e1 = __expf(v1 - m);
    float s = e0 + e1;
    for (int o = 32; o; o >>= 1) s += __shfl_xor(s, o);
    __shared__ float reds[4];
    if (lane == 0) reds[w] = s;
    __syncthreads();
    s = reds[0] + reds[1] + reds[2] + reds[3];

    float inv = 1.0f / s;
    P[(size_t)row * 512 + t]       = f2h(e0 * inv);
    P[(size_t)row * 512 + t + 256] = f2h(e1 * inv);
}

// ---------------------------------------------------------------------------
// Kernel 4: out = P*V + X (f32 out).  grid (32, 4, 8)
// ---------------------------------------------------------------------------
__global__ __launch_bounds__(256) void k_out(const u16* __restrict__ P,
                                             const u16* __restrict__ VT,
                                             const float* __restrict__ x,
                                             float* __restrict__ out)
{
    __shared__ u16 smem[8192];
    const int n0 = blockIdx.x * 128;
    const int m0 = blockIdx.y * 128;
    const int b  = blockIdx.z;

    const u16* Ap = P  + (size_t)b * 512 * 512 + (size_t)m0 * 512;
    const u16* Bp = VT + (size_t)b * 4096 * 512 + (size_t)n0 * 512;

    f32x4 acc[4][4];
    zero_acc(acc);
    gemm_nt_f16(smem, Ap, 512, Bp, 512, 512, acc);

    const int t = threadIdx.x, w = t >> 6, lane = t & 63;
    const int wm = (w >> 1) * 64, wn = (w & 1) * 64;
    const int cn = lane & 15, cq = lane >> 4;

#pragma unroll
    for (int mi = 0; mi < 4; mi++)
#pragma unroll
        for (int ni = 0; ni < 4; ni++)
#pragma unroll
            for (int r = 0; r < 4; r++) {
                int m = wm + mi * 16 + cq * 4 + r;
                int n = wn + ni * 16 + cn;
                size_t idx = ((size_t)b * 512 + m0 + m) * 4096 + n0 + n;
                out[idx] = acc[mi][ni][r] + x[idx];
            }
}

// ---------------------------------------------------------------------------
// ws layout (bytes), high-water ~140 MiB:
//   Wf  [3][512][512] f16    @ 0          (1572864)
//   XT  [8][4096][512] f16   @ 1572864    (33554432) — dead after k_qkv
//   Qh  [8][512][4096] f16   @ 35127296   (33554432)
//   Kh  [8][512][4096] f16   @ 68681728   (33554432)
//   VT  [8][4096][512] f16   @ 102236160  (33554432)
//   S   [4][8][512][512] f32 @ 1572864    (33554432) — overlaps dead XT
//   P   [8][512][512] f16    @ 135790592  (4194304)
// ---------------------------------------------------------------------------
extern "C" void kernel_launch(void* const* d_in, const int* in_sizes, int n_in,
                              void* d_out, int out_size, void* d_ws, size_t ws_size,
                              hipStream_t stream)
{
    const float* x  = (const float*)d_in[0];
    const float* wq = (const float*)d_in[1];
    const float* bq = (const float*)d_in[2];
    const float* wk = (const float*)d_in[3];
    const float* bk = (const float*)d_in[4];
    const float* wv = (const float*)d_in[5];
    const float* bv = (const float*)d_in[6];
    float* out = (float*)d_out;

    char* ws = (char*)d_ws;
    u16*  Wf = (u16*)(ws);
    u16*  XT = (u16*)(ws + 1572864);
    u16*  Qh = (u16*)(ws + 35127296);
    u16*  Kh = (u16*)(ws + 68681728);
    u16*  VT = (u16*)(ws + 102236160);
    float* S = (float*)(ws + 1572864);      // overlaps dead XT
    u16*  P  = (u16*)(ws + 135790592);

    k_convw<<<dim3(768), dim3(256), 0, stream>>>(wq, wk, wv, Wf);
    k_transpose<<<dim3(64, 8, 8), dim3(256), 0, stream>>>(x, XT);
    k_qkv<<<dim3(32, 8, 8), dim3(256), 0, stream>>>(Wf, bq, bk, bv, XT, Qh, Kh, VT);
    k_scores<<<dim3(4, 4, 32), dim3(256), 0, stream>>>(Qh, Kh, S);
    k_softmax<<<dim3(4096), dim3(256), 0, stream>>>(S, P);
    k_out<<<dim3(32, 4, 8), dim3(256), 0, stream>>>(P, VT, x, out);
}